// Round 9
// baseline (1138.274 us; speedup 1.0000x reference)
//
#include <hip/hip_runtime.h>
#include <math.h>

#define N_NODES 50000
#define N_EDGES 800000
#define ENC 64
#define ROUNDS 3
#define NEG_SLOPE 0.2f

typedef unsigned int u32;

__device__ __forceinline__ float lrelu(float m) {
  return m > 0.f ? m : NEG_SLOPE * m;
}

// ---------------- CSR build ----------------
__global__ void k_hist(const int* __restrict__ dst, int* __restrict__ deg) {
  int i = blockIdx.x * blockDim.x + threadIdx.x;
  int stride = gridDim.x * blockDim.x;
  for (; i < N_EDGES; i += stride) atomicAdd(&deg[dst[i]], 1);
}

#define SCAN_BLOCKS ((N_NODES + 255) / 256)  // 196

__global__ void __launch_bounds__(256) k_red(const int* __restrict__ deg,
                                             int* __restrict__ part) {
  __shared__ int sm[256];
  int bi = blockIdx.x, t = threadIdx.x;
  int i = bi * 256 + t;
  sm[t] = (i < N_NODES) ? deg[i] : 0;
  __syncthreads();
  for (int off = 128; off > 0; off >>= 1) {
    if (t < off) sm[t] += sm[t + off];
    __syncthreads();
  }
  if (t == 0) part[bi] = sm[0];
}

__global__ void __launch_bounds__(256) k_scanp(int* __restrict__ part) {
  __shared__ int sm[256];
  int t = threadIdx.x;
  int v = (t < SCAN_BLOCKS) ? part[t] : 0;
  sm[t] = v;
  __syncthreads();
  for (int off = 1; off < 256; off <<= 1) {
    int u = (t >= off) ? sm[t - off] : 0;
    __syncthreads();
    sm[t] += u;
    __syncthreads();
  }
  if (t < SCAN_BLOCKS) part[t] = sm[t] - v;  // exclusive
}

// degcur: degrees on entry, scatter cursors (= row_start) on exit.
__global__ void __launch_bounds__(256) k_csr(int* __restrict__ degcur,
                                             const int* __restrict__ part,
                                             int* __restrict__ row_start) {
  __shared__ int sm[256];
  int bi = blockIdx.x, t = threadIdx.x;
  int i = bi * 256 + t;
  int v = (i < N_NODES) ? degcur[i] : 0;
  sm[t] = v;
  __syncthreads();
  for (int off = 1; off < 256; off <<= 1) {
    int u = (t >= off) ? sm[t - off] : 0;
    __syncthreads();
    sm[t] += u;
    __syncthreads();
  }
  int excl = sm[t] - v + part[bi];
  if (i < N_NODES) {
    row_start[i] = excl;
    degcur[i] = excl;
    if (i == N_NODES - 1) row_start[N_NODES] = excl + v;
  }
}

// scatter ONLY 4B edge ids into CSR order (random 4B writes). The heavy 16B
// ea payload is moved by k_gather as random READS + coalesced writes instead
// (random RMW writes to HBM are far costlier than L3-resident gathers).
__global__ void k_scatter(const int* __restrict__ dst, int* __restrict__ cursor,
                          int* __restrict__ eid) {
  int i = blockIdx.x * blockDim.x + threadIdx.x;
  int stride = gridDim.x * blockDim.x;
  for (; i < N_EDGES; i += stride) {
    int pos = atomicAdd(&cursor[dst[i]], 1);
    eid[pos] = i;
  }
}

__global__ void k_gather(const int* __restrict__ eid, const int* __restrict__ src,
                         const float* __restrict__ ea, int* __restrict__ srcs,
                         float* __restrict__ ea_perm) {
  int i = blockIdx.x * blockDim.x + threadIdx.x;
  int stride = gridDim.x * blockDim.x;
  for (; i < N_EDGES; i += stride) {
    int e = eid[i];                                  // coalesced read
    srcs[i] = src[e];                                // random 4B read, coalesced write
    ((float4*)ea_perm)[i] = ((const float4*)ea)[e];  // random 16B read, coalesced write
  }
}

// ---------------- node encoder h0 = x@Wn + bn; block 0 also folds edge weights
// (wcomb = W_edge@We, bcomb = b_edge@We) -- merged to save a serialized dispatch.
__global__ void k_encode(const float* __restrict__ x, const float* __restrict__ Wn,
                         const float* __restrict__ bn, float* __restrict__ h0,
                         const float* __restrict__ W_edge, const float* __restrict__ b_edge,
                         const float* __restrict__ aWe, const float* __restrict__ cWe,
                         float* __restrict__ wcomb, float* __restrict__ bcomb) {
  __shared__ float lw[8 * ENC];
  __shared__ float lb[ENC];
  int t = threadIdx.x;
  if (blockIdx.x == 0) {  // tiny weight fold (runs alongside block 0's encode share)
    int i = t >> 6, d = t & 63;
    for (int sr = 0; sr < 6; ++sr) {
      const float* We = (sr < 3) ? (aWe + sr * ENC * ENC) : (cWe + (sr - 3) * ENC * ENC);
      float sum = 0.f;
      for (int k = 0; k < ENC; ++k) sum += W_edge[i * ENC + k] * We[k * ENC + d];
      wcomb[sr * 4 * ENC + i * ENC + d] = sum;
      if (t < ENC) {
        float bs = 0.f;
        for (int k = 0; k < ENC; ++k) bs += b_edge[k] * We[k * ENC + t];
        bcomb[sr * ENC + t] = bs;
      }
    }
  }
  for (int i = t; i < 8 * ENC; i += blockDim.x) lw[i] = Wn[i];
  if (t < ENC) lb[t] = bn[t];
  __syncthreads();
  int wid = t >> 6, lane = t & 63;
  int nwaves = (blockDim.x >> 6) * gridDim.x;
  int w = blockIdx.x * (blockDim.x >> 6) + wid;
  for (int n = w; n < N_NODES; n += nwaves) {
    const float4* xr4 = (const float4*)(x + n * 8);
    float4 a = xr4[0], b = xr4[1];
    float acc = lb[lane];
    acc += a.x * lw[0 * ENC + lane] + a.y * lw[1 * ENC + lane] +
           a.z * lw[2 * ENC + lane] + a.w * lw[3 * ENC + lane];
    acc += b.x * lw[4 * ENC + lane] + b.y * lw[5 * ENC + lane] +
           b.z * lw[6 * ENC + lane] + b.w * lw[7 * ENC + lane];
    h0[n * ENC + lane] = acc;
  }
}

// ---------------- per-round double GEMM, both stacks: blockIdx.y = stack.
// Middle design after r6 (LDS-issue-bound, weights re-read per 4 nodes) and r8
// (reg-weights, 140 VGPR -> 8.5% occupancy cliff): weights stay in LDS (zero
// VGPR cost, staged once, conflict-free b64 reads), amortized over 8-node
// chunks; h tile 64 nodes. LDS 48KB -> 3 blocks/CU; VGPR ~56 -> high occupancy.
// LDS:VALU ~ 1:5. Writes xl/xr STACK-INTERLEAVED [n][stack][64]. --------------
__global__ void __launch_bounds__(256) k_gemm2(const float* __restrict__ hinA,
                                               const float* __restrict__ hinC,
                                               const float* __restrict__ WlA,
                                               const float* __restrict__ WrA,
                                               const float* __restrict__ bcA,
                                               const float* __restrict__ WlC,
                                               const float* __restrict__ WrC,
                                               const float* __restrict__ bcC,
                                               float* __restrict__ xl_comb,
                                               float* __restrict__ xr_comb) {
  const int stk = blockIdx.y;
  const float* hin = stk ? hinC : hinA;
  const float* Wl = stk ? WlC : WlA;
  const float* Wr = stk ? WrC : WrA;
  const float* bc = stk ? bcC : bcA;
  __shared__ float lw[2 * ENC * ENC];  // 32 KB [mat][k][c]
  __shared__ float lh[64 * ENC];       // 16 KB [local node][k]
  int t = threadIdx.x;
  {  // stage weights: 2048 float4, fully coalesced
    const float4* wl4 = (const float4*)Wl;
    const float4* wr4 = (const float4*)Wr;
    float4* lw4 = (float4*)lw;
#pragma unroll
    for (int i = 0; i < 4; ++i) lw4[t + 256 * i] = wl4[t + 256 * i];
#pragma unroll
    for (int i = 0; i < 4; ++i) lw4[1024 + t + 256 * i] = wr4[t + 256 * i];
  }
  int base = blockIdx.x * 64;  // first node of tile
  {  // stage h tile: 1024 float4, fully coalesced; clamp OOB to a valid index
    const float4* h4 = (const float4*)hin;
    float4* lh4 = (float4*)lh;
    int maxi = N_NODES * 16 - 1;
#pragma unroll
    for (int i = 0; i < 4; ++i) {
      int idx = t + 256 * i;
      int gi = base * 16 + idx;
      if (gi > maxi) gi = maxi;
      lh4[idx] = h4[gi];
    }
  }
  __syncthreads();
  int wid = t >> 6, lane = t & 63;
  int msel = lane >> 5, cc = lane & 31;
  const float2* lw2 = (const float2*)lw;  // (m,k,cc) at m*2048 + k*32 + cc
  float* outp = (msel ? xr_comb : xl_comb) + stk * 64;  // interleaved row offset
  float2 bcv = make_float2(0.f, 0.f);
  if (msel) bcv = ((const float2*)bc)[cc];  // fold edge-encoder bias into xr
#pragma unroll
  for (int chunk = 0; chunk < 2; ++chunk) {
    int n0 = wid * 16 + chunk * 8;  // first local node of this 8-node chunk
    const float4* r0 = (const float4*)(lh + (n0 + 0) * ENC);
    const float4* r1 = (const float4*)(lh + (n0 + 1) * ENC);
    const float4* r2 = (const float4*)(lh + (n0 + 2) * ENC);
    const float4* r3 = (const float4*)(lh + (n0 + 3) * ENC);
    const float4* r4 = (const float4*)(lh + (n0 + 4) * ENC);
    const float4* r5 = (const float4*)(lh + (n0 + 5) * ENC);
    const float4* r6 = (const float4*)(lh + (n0 + 6) * ENC);
    const float4* r7 = (const float4*)(lh + (n0 + 7) * ENC);
    float2 a0 = {0.f, 0.f}, a1 = {0.f, 0.f}, a2 = {0.f, 0.f}, a3 = {0.f, 0.f};
    float2 a4 = {0.f, 0.f}, a5 = {0.f, 0.f}, a6 = {0.f, 0.f}, a7 = {0.f, 0.f};
#pragma unroll
    for (int k4 = 0; k4 < 16; ++k4) {
      float2 w0 = lw2[msel * 2048 + (k4 * 4 + 0) * 32 + cc];
      float2 w1 = lw2[msel * 2048 + (k4 * 4 + 1) * 32 + cc];
      float2 w2 = lw2[msel * 2048 + (k4 * 4 + 2) * 32 + cc];
      float2 w3 = lw2[msel * 2048 + (k4 * 4 + 3) * 32 + cc];
      float4 h;
      h = r0[k4];
      a0.x += h.x * w0.x + h.y * w1.x + h.z * w2.x + h.w * w3.x;
      a0.y += h.x * w0.y + h.y * w1.y + h.z * w2.y + h.w * w3.y;
      h = r1[k4];
      a1.x += h.x * w0.x + h.y * w1.x + h.z * w2.x + h.w * w3.x;
      a1.y += h.x * w0.y + h.y * w1.y + h.z * w2.y + h.w * w3.y;
      h = r2[k4];
      a2.x += h.x * w0.x + h.y * w1.x + h.z * w2.x + h.w * w3.x;
      a2.y += h.x * w0.y + h.y * w1.y + h.z * w2.y + h.w * w3.y;
      h = r3[k4];
      a3.x += h.x * w0.x + h.y * w1.x + h.z * w2.x + h.w * w3.x;
      a3.y += h.x * w0.y + h.y * w1.y + h.z * w2.y + h.w * w3.y;
      h = r4[k4];
      a4.x += h.x * w0.x + h.y * w1.x + h.z * w2.x + h.w * w3.x;
      a4.y += h.x * w0.y + h.y * w1.y + h.z * w2.y + h.w * w3.y;
      h = r5[k4];
      a5.x += h.x * w0.x + h.y * w1.x + h.z * w2.x + h.w * w3.x;
      a5.y += h.x * w0.y + h.y * w1.y + h.z * w2.y + h.w * w3.y;
      h = r6[k4];
      a6.x += h.x * w0.x + h.y * w1.x + h.z * w2.x + h.w * w3.x;
      a6.y += h.x * w0.y + h.y * w1.y + h.z * w2.y + h.w * w3.y;
      h = r7[k4];
      a7.x += h.x * w0.x + h.y * w1.x + h.z * w2.x + h.w * w3.x;
      a7.y += h.x * w0.y + h.y * w1.y + h.z * w2.y + h.w * w3.y;
    }
    int ng = base + n0;
    if (ng + 0 < N_NODES) *(float2*)(outp + (size_t)(ng + 0) * 128 + cc * 2) = make_float2(a0.x + bcv.x, a0.y + bcv.y);
    if (ng + 1 < N_NODES) *(float2*)(outp + (size_t)(ng + 1) * 128 + cc * 2) = make_float2(a1.x + bcv.x, a1.y + bcv.y);
    if (ng + 2 < N_NODES) *(float2*)(outp + (size_t)(ng + 2) * 128 + cc * 2) = make_float2(a2.x + bcv.x, a2.y + bcv.y);
    if (ng + 3 < N_NODES) *(float2*)(outp + (size_t)(ng + 3) * 128 + cc * 2) = make_float2(a3.x + bcv.x, a3.y + bcv.y);
    if (ng + 4 < N_NODES) *(float2*)(outp + (size_t)(ng + 4) * 128 + cc * 2) = make_float2(a4.x + bcv.x, a4.y + bcv.y);
    if (ng + 5 < N_NODES) *(float2*)(outp + (size_t)(ng + 5) * 128 + cc * 2) = make_float2(a5.x + bcv.x, a5.y + bcv.y);
    if (ng + 6 < N_NODES) *(float2*)(outp + (size_t)(ng + 6) * 128 + cc * 2) = make_float2(a6.x + bcv.x, a6.y + bcv.y);
    if (ng + 7 < N_NODES) *(float2*)(outp + (size_t)(ng + 7) * 128 + cc * 2) = make_float2(a7.x + bcv.x, a7.y + bcv.y);
  }
}

// ---------------- fused score + online softmax + aggregate ------------------
// Wave = dst node. Lane = {edge-slot g2(2)} x {stack sl(2)} x {channel-quad
// l16(16)}: each 32-lane half processes one edge; lanes 0-15 of the half do the
// actor stack, 16-31 the critic. ONE register set per lane, stack-selected via
// base pointers; chunk loads + shfl broadcasts shared by both stacks (round-5
// lesson: never duplicate shared chunk work). xl/xr stack-interleaved
// [n][2][64]: one contiguous 512B gather per edge. Never wave-uniform vector
// loads (round-1 lesson: ~50x amplification). RELU=0 (last round) fuses the
// decoders: outv IS the final h -> in-register 5-way actor dot + tanh and
// critic dot, 16-lane shfl reduce, lanes 0/16 write out; skips the h write.
template <int RELU>
__global__ void __launch_bounds__(256) k_attn(
    const int* __restrict__ row_start, const int* __restrict__ srcs,
    const float* __restrict__ ea_perm,
    const float* __restrict__ xl_comb, const float* __restrict__ xr_comb,
    const float* __restrict__ wca, const float* __restrict__ wcc,
    const float* __restrict__ atta, const float* __restrict__ attc,
    const float* __restrict__ Ba, const float* __restrict__ Bc,
    float* __restrict__ ha, float* __restrict__ hc,
    const float* __restrict__ Wdec, const float* __restrict__ badec,
    const float* __restrict__ Wvdec, const float* __restrict__ bvdec,
    float* __restrict__ out) {
  const float NEG_INF = __int_as_float(0xff800000u);
  int t = threadIdx.x;
  int wid = t >> 6, lane = t & 63;
  int g2 = lane >> 5;        // edge slot within wave
  int sl = (lane >> 4) & 1;  // stack (0=actor, 1=critic)
  int l16 = lane & 15;       // channel-quad index
  int q32 = lane & 31;       // quad index within interleaved 128-float row
  const float* wcS = sl ? wcc : wca;
  const float* attS = sl ? attc : atta;
  const float* BS = sl ? Bc : Ba;
  float* houtS = sl ? hc : ha;
  float4 w0 = ((const float4*)(wcS + 0 * ENC))[l16];
  float4 w1 = ((const float4*)(wcS + 1 * ENC))[l16];
  float4 w2 = ((const float4*)(wcS + 2 * ENC))[l16];
  float4 w3 = ((const float4*)(wcS + 3 * ENC))[l16];
  float4 at = ((const float4*)attS)[l16];
  float4 bv = ((const float4*)BS)[l16];
  // decode weights (RELU==0 instantiation only; DCE'd otherwise)
  float wd[20];
  float wv0 = 0.f, wv1 = 0.f, wv2 = 0.f, wv3 = 0.f;
  float bd0 = 0.f, bd1 = 0.f, bd2 = 0.f, bd3 = 0.f, bd4 = 0.f, bdv = 0.f;
  if constexpr (!RELU) {
    int c0 = l16 * 4;
    if (sl == 0) {
#pragma unroll
      for (int k = 0; k < 4; ++k)
#pragma unroll
        for (int j = 0; j < 5; ++j) wd[k * 5 + j] = Wdec[(c0 + k) * 5 + j];
      bd0 = badec[0]; bd1 = badec[1]; bd2 = badec[2]; bd3 = badec[3]; bd4 = badec[4];
    } else {
      wv0 = Wvdec[c0 + 0]; wv1 = Wvdec[c0 + 1];
      wv2 = Wvdec[c0 + 2]; wv3 = Wvdec[c0 + 3];
      bdv = bvdec[0];
    }
  }
  int nw = (blockDim.x >> 6) * gridDim.x;
  for (int n = blockIdx.x * (blockDim.x >> 6) + wid; n < N_NODES; n += nw) {
    int rs = row_start[n], re = row_start[n + 1];
    float4 outv;
    if (re > rs) {
      float4 xrn = ((const float4*)xr_comb)[(size_t)n * 32 + q32];
      float m = -1e30f, den = 0.f;
      float4 acc = make_float4(0.f, 0.f, 0.f, 0.f);
      // preload first chunk (register double-buffer)
      int cnt0 = re - rs; if (cnt0 > 16) cnt0 = 16;
      float eav = (lane < 4 * cnt0) ? ea_perm[(size_t)rs * 4 + lane] : 0.f;
      int sval = (lane < cnt0) ? srcs[rs + lane] : 0;
      for (int base = rs; base < re; base += 16) {
        int cnt = re - base; if (cnt > 16) cnt = 16;
        float eav_c = eav;
        int sval_c = sval;
        int nb = base + 16;
        if (nb < re) {  // wave-uniform prefetch of next chunk
          int cn = re - nb; if (cn > 16) cn = 16;
          eav = (lane < 4 * cn) ? ea_perm[(size_t)nb * 4 + lane] : 0.f;
          sval = (lane < cn) ? srcs[nb + lane] : 0;
        }
        // 16 edges = 4 pair-iterations x (2 edge slots x 2-deep unroll)
        for (int jp = 0; jp < 4; ++jp) {
          if (jp * 4 >= cnt) break;  // wave-uniform
          int jjA = jp * 4 + g2;
          int jjB = jjA + 2;
          bool actA = jjA < cnt, actB = jjB < cnt;
          int snA = __shfl(sval_c, actA ? jjA : 0);
          int snB = __shfl(sval_c, actB ? jjB : 0);
          // both gathers issued before use (ILP)
          float4 laA = ((const float4*)xl_comb)[(size_t)snA * 32 + q32];
          float4 laB = ((const float4*)xl_comb)[(size_t)snB * 32 + q32];
          float aA0 = __shfl(eav_c, jjA * 4 + 0);
          float aA1 = __shfl(eav_c, jjA * 4 + 1);
          float aA2 = __shfl(eav_c, jjA * 4 + 2);
          float aA3 = __shfl(eav_c, jjA * 4 + 3);
          float aB0 = __shfl(eav_c, jjB * 4 + 0);
          float aB1 = __shfl(eav_c, jjB * 4 + 1);
          float aB2 = __shfl(eav_c, jjB * 4 + 2);
          float aB3 = __shfl(eav_c, jjB * 4 + 3);
          // scores (4 channels/lane, one stack/lane), reduce within 16 lanes
          float pA = lrelu(laA.x + xrn.x + aA0 * w0.x + aA1 * w1.x + aA2 * w2.x + aA3 * w3.x) * at.x;
          pA += lrelu(laA.y + xrn.y + aA0 * w0.y + aA1 * w1.y + aA2 * w2.y + aA3 * w3.y) * at.y;
          pA += lrelu(laA.z + xrn.z + aA0 * w0.z + aA1 * w1.z + aA2 * w2.z + aA3 * w3.z) * at.z;
          pA += lrelu(laA.w + xrn.w + aA0 * w0.w + aA1 * w1.w + aA2 * w2.w + aA3 * w3.w) * at.w;
          float pB = lrelu(laB.x + xrn.x + aB0 * w0.x + aB1 * w1.x + aB2 * w2.x + aB3 * w3.x) * at.x;
          pB += lrelu(laB.y + xrn.y + aB0 * w0.y + aB1 * w1.y + aB2 * w2.y + aB3 * w3.y) * at.y;
          pB += lrelu(laB.z + xrn.z + aB0 * w0.z + aB1 * w1.z + aB2 * w2.z + aB3 * w3.z) * at.z;
          pB += lrelu(laB.w + xrn.w + aB0 * w0.w + aB1 * w1.w + aB2 * w2.w + aB3 * w3.w) * at.w;
          pA += __shfl_xor(pA, 1); pB += __shfl_xor(pB, 1);
          pA += __shfl_xor(pA, 2); pB += __shfl_xor(pB, 2);
          pA += __shfl_xor(pA, 4); pB += __shfl_xor(pB, 4);
          pA += __shfl_xor(pA, 8); pB += __shfl_xor(pB, 8);
          pA = actA ? pA : NEG_INF;
          pB = actB ? pB : NEG_INF;
          // two serial online-softmax updates (each serves 2 edges x 2 stacks)
          {
            float mn = fmaxf(m, pA);
            float sc = __expf(m - mn);
            float ex = __expf(pA - mn);
            den = den * sc + ex;
            acc.x = acc.x * sc + ex * laA.x;
            acc.y = acc.y * sc + ex * laA.y;
            acc.z = acc.z * sc + ex * laA.z;
            acc.w = acc.w * sc + ex * laA.w;
            m = mn;
          }
          {
            float mn = fmaxf(m, pB);
            float sc = __expf(m - mn);
            float ex = __expf(pB - mn);
            den = den * sc + ex;
            acc.x = acc.x * sc + ex * laB.x;
            acc.y = acc.y * sc + ex * laB.y;
            acc.z = acc.z * sc + ex * laB.z;
            acc.w = acc.w * sc + ex * laB.w;
            m = mn;
          }
        }
      }
      // merge the 2 edge-slot states (xor 32; stacks stay in their lanes)
      {
        float m2 = __shfl_xor(m, 32);
        float dn2 = __shfl_xor(den, 32);
        float a2x = __shfl_xor(acc.x, 32), a2y = __shfl_xor(acc.y, 32);
        float a2z = __shfl_xor(acc.z, 32), a2w = __shfl_xor(acc.w, 32);
        float mn = fmaxf(m, m2);
        float s1 = __expf(m - mn), s2 = __expf(m2 - mn);
        den = den * s1 + dn2 * s2;
        acc.x = acc.x * s1 + a2x * s2;
        acc.y = acc.y * s1 + a2y * s2;
        acc.z = acc.z * s1 + a2z * s2;
        acc.w = acc.w * s1 + a2w * s2;
      }
      float inv = 1.f / den;
      outv = make_float4(acc.x * inv + bv.x, acc.y * inv + bv.y,
                         acc.z * inv + bv.z, acc.w * inv + bv.w);
    } else {
      outv = bv;
    }
    if constexpr (RELU) {
      outv.x = fmaxf(outv.x, 0.f);
      outv.y = fmaxf(outv.y, 0.f);
      outv.z = fmaxf(outv.z, 0.f);
      outv.w = fmaxf(outv.w, 0.f);
      if (g2 == 0) ((float4*)houtS)[(size_t)n * 16 + l16] = outv;
    } else {
      // fused decode: actor lanes 5 partial dots, critic lanes 1
      float p0, p1, p2, p3, p4;
      if (sl == 0) {
        p0 = outv.x * wd[0] + outv.y * wd[5] + outv.z * wd[10] + outv.w * wd[15];
        p1 = outv.x * wd[1] + outv.y * wd[6] + outv.z * wd[11] + outv.w * wd[16];
        p2 = outv.x * wd[2] + outv.y * wd[7] + outv.z * wd[12] + outv.w * wd[17];
        p3 = outv.x * wd[3] + outv.y * wd[8] + outv.z * wd[13] + outv.w * wd[18];
        p4 = outv.x * wd[4] + outv.y * wd[9] + outv.z * wd[14] + outv.w * wd[19];
      } else {
        p0 = outv.x * wv0 + outv.y * wv1 + outv.z * wv2 + outv.w * wv3;
        p1 = p2 = p3 = p4 = 0.f;
      }
#pragma unroll
      for (int d = 1; d <= 8; d <<= 1) {
        p0 += __shfl_xor(p0, d);
        p1 += __shfl_xor(p1, d);
        p2 += __shfl_xor(p2, d);
        p3 += __shfl_xor(p3, d);
        p4 += __shfl_xor(p4, d);
      }
      if (g2 == 0 && l16 == 0) {
        if (sl == 0) {
          out[n * 6 + 0] = tanhf(p0 + bd0);
          out[n * 6 + 1] = tanhf(p1 + bd1);
          out[n * 6 + 2] = tanhf(p2 + bd2);
          out[n * 6 + 3] = tanhf(p3 + bd3);
          out[n * 6 + 4] = tanhf(p4 + bd4);
        } else {
          out[n * 6 + 5] = p0 + bdv;
        }
      }
    }
  }
}

extern "C" void kernel_launch(void* const* d_in, const int* in_sizes, int n_in,
                              void* d_out, int out_size, void* d_ws, size_t ws_size,
                              hipStream_t stream) {
  const float* x    = (const float*)d_in[0];
  const float* ea   = (const float*)d_in[1];
  const float* Wn   = (const float*)d_in[2];
  const float* bn   = (const float*)d_in[3];
  const float* Wedg = (const float*)d_in[4];
  const float* bedg = (const float*)d_in[5];
  const float* aWl  = (const float*)d_in[6];
  const float* aWr  = (const float*)d_in[7];
  const float* aWe  = (const float*)d_in[8];
  const float* aAtt = (const float*)d_in[9];
  const float* aB   = (const float*)d_in[10];
  const float* cWl  = (const float*)d_in[11];
  const float* cWr  = (const float*)d_in[12];
  const float* cWe  = (const float*)d_in[13];
  const float* cAtt = (const float*)d_in[14];
  const float* cB   = (const float*)d_in[15];
  const float* Wa   = (const float*)d_in[16];
  const float* ba   = (const float*)d_in[17];
  const float* Wv   = (const float*)d_in[18];
  const float* bv   = (const float*)d_in[19];
  const int* src    = (const int*)d_in[20];
  const int* dst    = (const int*)d_in[21];
  float* out = (float*)d_out;

  char* w = (char*)d_ws;
  size_t off = 0;
  auto alloc = [&](size_t bytes) -> char* {
    char* p = w + off;
    off = (off + bytes + 255) & ~(size_t)255;
    return p;
  };
  float* h0  = (float*)alloc((size_t)N_NODES * ENC * 4);
  float* hA  = (float*)alloc((size_t)N_NODES * ENC * 4);
  float* hC  = (float*)alloc((size_t)N_NODES * ENC * 4);
  float* xl_comb = (float*)alloc((size_t)N_NODES * 2 * ENC * 4);  // [n][stack][64]
  float* xr_comb = (float*)alloc((size_t)N_NODES * 2 * ENC * 4);  // [n][stack][64]
  int* eid       = (int*)alloc((size_t)N_EDGES * 4);
  int* srcs      = (int*)alloc((size_t)N_EDGES * 4);
  float* ea_perm = (float*)alloc((size_t)N_EDGES * 16);
  int* row_start = (int*)alloc((size_t)(N_NODES + 1) * 4);
  int* cursor    = (int*)alloc((size_t)N_NODES * 4);
  int* part      = (int*)alloc(256 * 4);
  float* wcomb   = (float*)alloc(6 * 4 * ENC * 4);
  float* bcomb   = (float*)alloc(6 * ENC * 4);

  // ---- CSR build ----
  hipMemsetAsync(cursor, 0, (size_t)N_NODES * 4, stream);
  k_hist<<<2048, 256, 0, stream>>>(dst, cursor);
  k_red<<<SCAN_BLOCKS, 256, 0, stream>>>(cursor, part);
  k_scanp<<<1, 256, 0, stream>>>(part);
  k_csr<<<SCAN_BLOCKS, 256, 0, stream>>>(cursor, part, row_start);
  k_scatter<<<2048, 256, 0, stream>>>(dst, cursor, eid);
  k_gather<<<2048, 256, 0, stream>>>(eid, src, ea, srcs, ea_perm);

  // ---- encoder (+ folded edge weights in block 0) ----
  k_encode<<<512, 256, 0, stream>>>(x, Wn, bn, h0, Wedg, bedg, aWe, cWe, wcomb, bcomb);

  const int GEMM_TILES = (N_NODES + 63) / 64;  // 782

  for (int r = 0; r < ROUNDS; ++r) {
    const float* hinA = (r == 0) ? h0 : hA;
    const float* hinC = (r == 0) ? h0 : hC;
    k_gemm2<<<dim3(GEMM_TILES, 2), 256, 0, stream>>>(
        hinA, hinC, aWl + r * ENC * ENC, aWr + r * ENC * ENC, bcomb + r * ENC,
        cWl + r * ENC * ENC, cWr + r * ENC * ENC, bcomb + (3 + r) * ENC,
        xl_comb, xr_comb);
    if (r < ROUNDS - 1)
      k_attn<1><<<2048, 256, 0, stream>>>(row_start, srcs, ea_perm, xl_comb, xr_comb,
                                          wcomb + r * 4 * ENC, wcomb + (3 + r) * 4 * ENC,
                                          aAtt + r * ENC, cAtt + r * ENC,
                                          aB + r * ENC, cB + r * ENC, hA, hC,
                                          Wa, ba, Wv, bv, out);
    else
      k_attn<0><<<2048, 256, 0, stream>>>(row_start, srcs, ea_perm, xl_comb, xr_comb,
                                          wcomb + r * 4 * ENC, wcomb + (3 + r) * 4 * ENC,
                                          aAtt + r * ENC, cAtt + r * ENC,
                                          aB + r * ENC, cB + r * ENC, hA, hC,
                                          Wa, ba, Wv, bv, out);
  }
}

// Round 10
// 698.085 us; speedup vs baseline: 1.6306x; 1.6306x over previous
//
#include <hip/hip_runtime.h>
#include <math.h>

#define N_NODES 50000
#define N_EDGES 800000
#define ENC 64
#define ROUNDS 3
#define NEG_SLOPE 0.2f

typedef unsigned int u32;

__device__ __forceinline__ float lrelu(float m) {
  return m > 0.f ? m : NEG_SLOPE * m;
}

// ---------------- CSR build ----------------
__global__ void k_hist(const int* __restrict__ dst, int* __restrict__ deg) {
  int i = blockIdx.x * blockDim.x + threadIdx.x;
  int stride = gridDim.x * blockDim.x;
  for (; i < N_EDGES; i += stride) atomicAdd(&deg[dst[i]], 1);
}

#define SCAN_BLOCKS ((N_NODES + 255) / 256)  // 196

__global__ void __launch_bounds__(256) k_red(const int* __restrict__ deg,
                                             int* __restrict__ part) {
  __shared__ int sm[256];
  int bi = blockIdx.x, t = threadIdx.x;
  int i = bi * 256 + t;
  sm[t] = (i < N_NODES) ? deg[i] : 0;
  __syncthreads();
  for (int off = 128; off > 0; off >>= 1) {
    if (t < off) sm[t] += sm[t + off];
    __syncthreads();
  }
  if (t == 0) part[bi] = sm[0];
}

__global__ void __launch_bounds__(256) k_scanp(int* __restrict__ part) {
  __shared__ int sm[256];
  int t = threadIdx.x;
  int v = (t < SCAN_BLOCKS) ? part[t] : 0;
  sm[t] = v;
  __syncthreads();
  for (int off = 1; off < 256; off <<= 1) {
    int u = (t >= off) ? sm[t - off] : 0;
    __syncthreads();
    sm[t] += u;
    __syncthreads();
  }
  if (t < SCAN_BLOCKS) part[t] = sm[t] - v;  // exclusive
}

// degcur: degrees on entry, scatter cursors (= row_start) on exit.
__global__ void __launch_bounds__(256) k_csr(int* __restrict__ degcur,
                                             const int* __restrict__ part,
                                             int* __restrict__ row_start) {
  __shared__ int sm[256];
  int bi = blockIdx.x, t = threadIdx.x;
  int i = bi * 256 + t;
  int v = (i < N_NODES) ? degcur[i] : 0;
  sm[t] = v;
  __syncthreads();
  for (int off = 1; off < 256; off <<= 1) {
    int u = (t >= off) ? sm[t - off] : 0;
    __syncthreads();
    sm[t] += u;
    __syncthreads();
  }
  int excl = sm[t] - v + part[bi];
  if (i < N_NODES) {
    row_start[i] = excl;
    degcur[i] = excl;
    if (i == N_NODES - 1) row_start[N_NODES] = excl + v;
  }
}

// scatter ONLY 4B edge ids into CSR order (random 4B writes). The heavy 16B
// ea payload is moved by k_gather as random READS + coalesced writes instead.
__global__ void k_scatter(const int* __restrict__ dst, int* __restrict__ cursor,
                          int* __restrict__ eid) {
  int i = blockIdx.x * blockDim.x + threadIdx.x;
  int stride = gridDim.x * blockDim.x;
  for (; i < N_EDGES; i += stride) {
    int pos = atomicAdd(&cursor[dst[i]], 1);
    eid[pos] = i;
  }
}

__global__ void k_gather(const int* __restrict__ eid, const int* __restrict__ src,
                         const float* __restrict__ ea, int* __restrict__ srcs,
                         float* __restrict__ ea_perm) {
  int i = blockIdx.x * blockDim.x + threadIdx.x;
  int stride = gridDim.x * blockDim.x;
  for (; i < N_EDGES; i += stride) {
    int e = eid[i];                                  // coalesced read
    srcs[i] = src[e];                                // random 4B read, coalesced write
    ((float4*)ea_perm)[i] = ((const float4*)ea)[e];  // random 16B read, coalesced write
  }
}

// ---------------- node encoder h0 = x@Wn + bn; block 0 also folds edge weights
__global__ void k_encode(const float* __restrict__ x, const float* __restrict__ Wn,
                         const float* __restrict__ bn, float* __restrict__ h0,
                         const float* __restrict__ W_edge, const float* __restrict__ b_edge,
                         const float* __restrict__ aWe, const float* __restrict__ cWe,
                         float* __restrict__ wcomb, float* __restrict__ bcomb) {
  __shared__ float lw[8 * ENC];
  __shared__ float lb[ENC];
  int t = threadIdx.x;
  if (blockIdx.x == 0) {  // tiny weight fold (runs alongside block 0's encode share)
    int i = t >> 6, d = t & 63;
    for (int sr = 0; sr < 6; ++sr) {
      const float* We = (sr < 3) ? (aWe + sr * ENC * ENC) : (cWe + (sr - 3) * ENC * ENC);
      float sum = 0.f;
      for (int k = 0; k < ENC; ++k) sum += W_edge[i * ENC + k] * We[k * ENC + d];
      wcomb[sr * 4 * ENC + i * ENC + d] = sum;
      if (t < ENC) {
        float bs = 0.f;
        for (int k = 0; k < ENC; ++k) bs += b_edge[k] * We[k * ENC + t];
        bcomb[sr * ENC + t] = bs;
      }
    }
  }
  for (int i = t; i < 8 * ENC; i += blockDim.x) lw[i] = Wn[i];
  if (t < ENC) lb[t] = bn[t];
  __syncthreads();
  int wid = t >> 6, lane = t & 63;
  int nwaves = (blockDim.x >> 6) * gridDim.x;
  int w = blockIdx.x * (blockDim.x >> 6) + wid;
  for (int n = w; n < N_NODES; n += nwaves) {
    const float4* xr4 = (const float4*)(x + n * 8);
    float4 a = xr4[0], b = xr4[1];
    float acc = lb[lane];
    acc += a.x * lw[0 * ENC + lane] + a.y * lw[1 * ENC + lane] +
           a.z * lw[2 * ENC + lane] + a.w * lw[3 * ENC + lane];
    acc += b.x * lw[4 * ENC + lane] + b.y * lw[5 * ENC + lane] +
           b.z * lw[6 * ENC + lane] + b.w * lw[7 * ENC + lane];
    h0[n * ENC + lane] = acc;
  }
}

// ---------------- per-round double GEMM, both stacks: blockIdx.y = stack.
// REVERTED to the round-6 design (best measured: ~78us/dispatch, never top-5).
// r7 128-tile (+8us), r8 reg-weights (140 VGPR, 8.5% occ, 104us), r9 8-node
// unroll (256 VGPR + scratch spill, 222us) all regressed. 64-node tile,
// weights+h in LDS (48KB, 3 blocks/CU), 4-node chunks, 4-deep FMA ILP.
// Writes xl/xr STACK-INTERLEAVED [n][stack][64] for attn's 512B gathers. ----
__global__ void __launch_bounds__(256) k_gemm2(const float* __restrict__ hinA,
                                               const float* __restrict__ hinC,
                                               const float* __restrict__ WlA,
                                               const float* __restrict__ WrA,
                                               const float* __restrict__ bcA,
                                               const float* __restrict__ WlC,
                                               const float* __restrict__ WrC,
                                               const float* __restrict__ bcC,
                                               float* __restrict__ xl_comb,
                                               float* __restrict__ xr_comb) {
  const int stk = blockIdx.y;
  const float* hin = stk ? hinC : hinA;
  const float* Wl = stk ? WlC : WlA;
  const float* Wr = stk ? WrC : WrA;
  const float* bc = stk ? bcC : bcA;
  __shared__ float lw[2 * ENC * ENC];  // 32 KB [mat][k][c]
  __shared__ float lh[64 * ENC];       // 16 KB [local node][k]
  int t = threadIdx.x;
  {  // stage weights: 2048 float4, fully coalesced
    const float4* wl4 = (const float4*)Wl;
    const float4* wr4 = (const float4*)Wr;
    float4* lw4 = (float4*)lw;
#pragma unroll
    for (int i = 0; i < 4; ++i) lw4[t + 256 * i] = wl4[t + 256 * i];
#pragma unroll
    for (int i = 0; i < 4; ++i) lw4[1024 + t + 256 * i] = wr4[t + 256 * i];
  }
  int base = blockIdx.x * 64;  // first node of tile
  {  // stage h tile: 1024 float4, fully coalesced; clamp OOB to a valid index
    const float4* h4 = (const float4*)hin;
    float4* lh4 = (float4*)lh;
    int maxi = N_NODES * 16 - 1;
#pragma unroll
    for (int i = 0; i < 4; ++i) {
      int idx = t + 256 * i;
      int gi = base * 16 + idx;
      if (gi > maxi) gi = maxi;
      lh4[idx] = h4[gi];
    }
  }
  __syncthreads();
  int wid = t >> 6, lane = t & 63;
  int msel = lane >> 5, cc = lane & 31;
  const float2* lw2 = (const float2*)lw;  // (m,k,cc) at m*2048 + k*32 + cc
  float* outp = (msel ? xr_comb : xl_comb) + stk * 64;  // interleaved row offset
  float2 bcv = make_float2(0.f, 0.f);
  if (msel) bcv = ((const float2*)bc)[cc];  // fold edge-encoder bias into xr
#pragma unroll
  for (int chunk = 0; chunk < 4; ++chunk) {
    int n0 = wid * 16 + chunk * 4;  // local node of this 4-node chunk
    float a00 = 0.f, a01 = 0.f, a10 = 0.f, a11 = 0.f;
    float a20 = 0.f, a21 = 0.f, a30 = 0.f, a31 = 0.f;
    const float4* r0 = (const float4*)(lh + (n0 + 0) * ENC);
    const float4* r1 = (const float4*)(lh + (n0 + 1) * ENC);
    const float4* r2 = (const float4*)(lh + (n0 + 2) * ENC);
    const float4* r3 = (const float4*)(lh + (n0 + 3) * ENC);
#pragma unroll
    for (int k4 = 0; k4 < 16; ++k4) {
      float4 h0 = r0[k4], h1 = r1[k4], h2 = r2[k4], h3 = r3[k4];
      float2 w0 = lw2[msel * 2048 + (k4 * 4 + 0) * 32 + cc];
      float2 w1 = lw2[msel * 2048 + (k4 * 4 + 1) * 32 + cc];
      float2 w2 = lw2[msel * 2048 + (k4 * 4 + 2) * 32 + cc];
      float2 w3 = lw2[msel * 2048 + (k4 * 4 + 3) * 32 + cc];
      a00 += h0.x * w0.x + h0.y * w1.x + h0.z * w2.x + h0.w * w3.x;
      a01 += h0.x * w0.y + h0.y * w1.y + h0.z * w2.y + h0.w * w3.y;
      a10 += h1.x * w0.x + h1.y * w1.x + h1.z * w2.x + h1.w * w3.x;
      a11 += h1.x * w0.y + h1.y * w1.y + h1.z * w2.y + h1.w * w3.y;
      a20 += h2.x * w0.x + h2.y * w1.x + h2.z * w2.x + h2.w * w3.x;
      a21 += h2.x * w0.y + h2.y * w1.y + h2.z * w2.y + h2.w * w3.y;
      a30 += h3.x * w0.x + h3.y * w1.x + h3.z * w2.x + h3.w * w3.x;
      a31 += h3.x * w0.y + h3.y * w1.y + h3.z * w2.y + h3.w * w3.y;
    }
    int ng = base + n0;
    if (ng + 0 < N_NODES) *(float2*)(outp + (size_t)(ng + 0) * 128 + cc * 2) = make_float2(a00 + bcv.x, a01 + bcv.y);
    if (ng + 1 < N_NODES) *(float2*)(outp + (size_t)(ng + 1) * 128 + cc * 2) = make_float2(a10 + bcv.x, a11 + bcv.y);
    if (ng + 2 < N_NODES) *(float2*)(outp + (size_t)(ng + 2) * 128 + cc * 2) = make_float2(a20 + bcv.x, a21 + bcv.y);
    if (ng + 3 < N_NODES) *(float2*)(outp + (size_t)(ng + 3) * 128 + cc * 2) = make_float2(a30 + bcv.x, a31 + bcv.y);
  }
}

// ---------------- fused score + online softmax + aggregate ------------------
// Wave = dst node. Lane = {edge-slot g2(2)} x {stack sl(2)} x {channel-quad
// l16(16)}. One register set per lane (stack-selected); chunk loads + shfl
// broadcasts shared by both stacks (r5 lesson). xl/xr stack-interleaved
// [n][2][64]: one contiguous 512B gather per edge. Never wave-uniform vector
// loads (r1 lesson: ~50x amplification). RELU=0 fuses the decoders.
template <int RELU>
__global__ void __launch_bounds__(256) k_attn(
    const int* __restrict__ row_start, const int* __restrict__ srcs,
    const float* __restrict__ ea_perm,
    const float* __restrict__ xl_comb, const float* __restrict__ xr_comb,
    const float* __restrict__ wca, const float* __restrict__ wcc,
    const float* __restrict__ atta, const float* __restrict__ attc,
    const float* __restrict__ Ba, const float* __restrict__ Bc,
    float* __restrict__ ha, float* __restrict__ hc,
    const float* __restrict__ Wdec, const float* __restrict__ badec,
    const float* __restrict__ Wvdec, const float* __restrict__ bvdec,
    float* __restrict__ out) {
  const float NEG_INF = __int_as_float(0xff800000u);
  int t = threadIdx.x;
  int wid = t >> 6, lane = t & 63;
  int g2 = lane >> 5;        // edge slot within wave
  int sl = (lane >> 4) & 1;  // stack (0=actor, 1=critic)
  int l16 = lane & 15;       // channel-quad index
  int q32 = lane & 31;       // quad index within interleaved 128-float row
  const float* wcS = sl ? wcc : wca;
  const float* attS = sl ? attc : atta;
  const float* BS = sl ? Bc : Ba;
  float* houtS = sl ? hc : ha;
  float4 w0 = ((const float4*)(wcS + 0 * ENC))[l16];
  float4 w1 = ((const float4*)(wcS + 1 * ENC))[l16];
  float4 w2 = ((const float4*)(wcS + 2 * ENC))[l16];
  float4 w3 = ((const float4*)(wcS + 3 * ENC))[l16];
  float4 at = ((const float4*)attS)[l16];
  float4 bv = ((const float4*)BS)[l16];
  // decode weights (RELU==0 instantiation only; DCE'd otherwise)
  float wd[20];
  float wv0 = 0.f, wv1 = 0.f, wv2 = 0.f, wv3 = 0.f;
  float bd0 = 0.f, bd1 = 0.f, bd2 = 0.f, bd3 = 0.f, bd4 = 0.f, bdv = 0.f;
  if constexpr (!RELU) {
    int c0 = l16 * 4;
    if (sl == 0) {
#pragma unroll
      for (int k = 0; k < 4; ++k)
#pragma unroll
        for (int j = 0; j < 5; ++j) wd[k * 5 + j] = Wdec[(c0 + k) * 5 + j];
      bd0 = badec[0]; bd1 = badec[1]; bd2 = badec[2]; bd3 = badec[3]; bd4 = badec[4];
    } else {
      wv0 = Wvdec[c0 + 0]; wv1 = Wvdec[c0 + 1];
      wv2 = Wvdec[c0 + 2]; wv3 = Wvdec[c0 + 3];
      bdv = bvdec[0];
    }
  }
  int nw = (blockDim.x >> 6) * gridDim.x;
  for (int n = blockIdx.x * (blockDim.x >> 6) + wid; n < N_NODES; n += nw) {
    int rs = row_start[n], re = row_start[n + 1];
    float4 outv;
    if (re > rs) {
      float4 xrn = ((const float4*)xr_comb)[(size_t)n * 32 + q32];
      float m = -1e30f, den = 0.f;
      float4 acc = make_float4(0.f, 0.f, 0.f, 0.f);
      // preload first chunk (register double-buffer)
      int cnt0 = re - rs; if (cnt0 > 16) cnt0 = 16;
      float eav = (lane < 4 * cnt0) ? ea_perm[(size_t)rs * 4 + lane] : 0.f;
      int sval = (lane < cnt0) ? srcs[rs + lane] : 0;
      for (int base = rs; base < re; base += 16) {
        int cnt = re - base; if (cnt > 16) cnt = 16;
        float eav_c = eav;
        int sval_c = sval;
        int nb = base + 16;
        if (nb < re) {  // wave-uniform prefetch of next chunk
          int cn = re - nb; if (cn > 16) cn = 16;
          eav = (lane < 4 * cn) ? ea_perm[(size_t)nb * 4 + lane] : 0.f;
          sval = (lane < cn) ? srcs[nb + lane] : 0;
        }
        // 16 edges = 4 pair-iterations x (2 edge slots x 2-deep unroll)
        for (int jp = 0; jp < 4; ++jp) {
          if (jp * 4 >= cnt) break;  // wave-uniform
          int jjA = jp * 4 + g2;
          int jjB = jjA + 2;
          bool actA = jjA < cnt, actB = jjB < cnt;
          int snA = __shfl(sval_c, actA ? jjA : 0);
          int snB = __shfl(sval_c, actB ? jjB : 0);
          // both gathers issued before use (ILP)
          float4 laA = ((const float4*)xl_comb)[(size_t)snA * 32 + q32];
          float4 laB = ((const float4*)xl_comb)[(size_t)snB * 32 + q32];
          float aA0 = __shfl(eav_c, jjA * 4 + 0);
          float aA1 = __shfl(eav_c, jjA * 4 + 1);
          float aA2 = __shfl(eav_c, jjA * 4 + 2);
          float aA3 = __shfl(eav_c, jjA * 4 + 3);
          float aB0 = __shfl(eav_c, jjB * 4 + 0);
          float aB1 = __shfl(eav_c, jjB * 4 + 1);
          float aB2 = __shfl(eav_c, jjB * 4 + 2);
          float aB3 = __shfl(eav_c, jjB * 4 + 3);
          // scores (4 channels/lane, one stack/lane), reduce within 16 lanes
          float pA = lrelu(laA.x + xrn.x + aA0 * w0.x + aA1 * w1.x + aA2 * w2.x + aA3 * w3.x) * at.x;
          pA += lrelu(laA.y + xrn.y + aA0 * w0.y + aA1 * w1.y + aA2 * w2.y + aA3 * w3.y) * at.y;
          pA += lrelu(laA.z + xrn.z + aA0 * w0.z + aA1 * w1.z + aA2 * w2.z + aA3 * w3.z) * at.z;
          pA += lrelu(laA.w + xrn.w + aA0 * w0.w + aA1 * w1.w + aA2 * w2.w + aA3 * w3.w) * at.w;
          float pB = lrelu(laB.x + xrn.x + aB0 * w0.x + aB1 * w1.x + aB2 * w2.x + aB3 * w3.x) * at.x;
          pB += lrelu(laB.y + xrn.y + aB0 * w0.y + aB1 * w1.y + aB2 * w2.y + aB3 * w3.y) * at.y;
          pB += lrelu(laB.z + xrn.z + aB0 * w0.z + aB1 * w1.z + aB2 * w2.z + aB3 * w3.z) * at.z;
          pB += lrelu(laB.w + xrn.w + aB0 * w0.w + aB1 * w1.w + aB2 * w2.w + aB3 * w3.w) * at.w;
          pA += __shfl_xor(pA, 1); pB += __shfl_xor(pB, 1);
          pA += __shfl_xor(pA, 2); pB += __shfl_xor(pB, 2);
          pA += __shfl_xor(pA, 4); pB += __shfl_xor(pB, 4);
          pA += __shfl_xor(pA, 8); pB += __shfl_xor(pB, 8);
          pA = actA ? pA : NEG_INF;
          pB = actB ? pB : NEG_INF;
          // two serial online-softmax updates (each serves 2 edges x 2 stacks)
          {
            float mn = fmaxf(m, pA);
            float sc = __expf(m - mn);
            float ex = __expf(pA - mn);
            den = den * sc + ex;
            acc.x = acc.x * sc + ex * laA.x;
            acc.y = acc.y * sc + ex * laA.y;
            acc.z = acc.z * sc + ex * laA.z;
            acc.w = acc.w * sc + ex * laA.w;
            m = mn;
          }
          {
            float mn = fmaxf(m, pB);
            float sc = __expf(m - mn);
            float ex = __expf(pB - mn);
            den = den * sc + ex;
            acc.x = acc.x * sc + ex * laB.x;
            acc.y = acc.y * sc + ex * laB.y;
            acc.z = acc.z * sc + ex * laB.z;
            acc.w = acc.w * sc + ex * laB.w;
            m = mn;
          }
        }
      }
      // merge the 2 edge-slot states (xor 32; stacks stay in their lanes)
      {
        float m2 = __shfl_xor(m, 32);
        float dn2 = __shfl_xor(den, 32);
        float a2x = __shfl_xor(acc.x, 32), a2y = __shfl_xor(acc.y, 32);
        float a2z = __shfl_xor(acc.z, 32), a2w = __shfl_xor(acc.w, 32);
        float mn = fmaxf(m, m2);
        float s1 = __expf(m - mn), s2 = __expf(m2 - mn);
        den = den * s1 + dn2 * s2;
        acc.x = acc.x * s1 + a2x * s2;
        acc.y = acc.y * s1 + a2y * s2;
        acc.z = acc.z * s1 + a2z * s2;
        acc.w = acc.w * s1 + a2w * s2;
      }
      float inv = 1.f / den;
      outv = make_float4(acc.x * inv + bv.x, acc.y * inv + bv.y,
                         acc.z * inv + bv.z, acc.w * inv + bv.w);
    } else {
      outv = bv;
    }
    if constexpr (RELU) {
      outv.x = fmaxf(outv.x, 0.f);
      outv.y = fmaxf(outv.y, 0.f);
      outv.z = fmaxf(outv.z, 0.f);
      outv.w = fmaxf(outv.w, 0.f);
      if (g2 == 0) ((float4*)houtS)[(size_t)n * 16 + l16] = outv;
    } else {
      // fused decode: actor lanes 5 partial dots, critic lanes 1
      float p0, p1, p2, p3, p4;
      if (sl == 0) {
        p0 = outv.x * wd[0] + outv.y * wd[5] + outv.z * wd[10] + outv.w * wd[15];
        p1 = outv.x * wd[1] + outv.y * wd[6] + outv.z * wd[11] + outv.w * wd[16];
        p2 = outv.x * wd[2] + outv.y * wd[7] + outv.z * wd[12] + outv.w * wd[17];
        p3 = outv.x * wd[3] + outv.y * wd[8] + outv.z * wd[13] + outv.w * wd[18];
        p4 = outv.x * wd[4] + outv.y * wd[9] + outv.z * wd[14] + outv.w * wd[19];
      } else {
        p0 = outv.x * wv0 + outv.y * wv1 + outv.z * wv2 + outv.w * wv3;
        p1 = p2 = p3 = p4 = 0.f;
      }
#pragma unroll
      for (int d = 1; d <= 8; d <<= 1) {
        p0 += __shfl_xor(p0, d);
        p1 += __shfl_xor(p1, d);
        p2 += __shfl_xor(p2, d);
        p3 += __shfl_xor(p3, d);
        p4 += __shfl_xor(p4, d);
      }
      if (g2 == 0 && l16 == 0) {
        if (sl == 0) {
          out[n * 6 + 0] = tanhf(p0 + bd0);
          out[n * 6 + 1] = tanhf(p1 + bd1);
          out[n * 6 + 2] = tanhf(p2 + bd2);
          out[n * 6 + 3] = tanhf(p3 + bd3);
          out[n * 6 + 4] = tanhf(p4 + bd4);
        } else {
          out[n * 6 + 5] = p0 + bdv;
        }
      }
    }
  }
}

extern "C" void kernel_launch(void* const* d_in, const int* in_sizes, int n_in,
                              void* d_out, int out_size, void* d_ws, size_t ws_size,
                              hipStream_t stream) {
  const float* x    = (const float*)d_in[0];
  const float* ea   = (const float*)d_in[1];
  const float* Wn   = (const float*)d_in[2];
  const float* bn   = (const float*)d_in[3];
  const float* Wedg = (const float*)d_in[4];
  const float* bedg = (const float*)d_in[5];
  const float* aWl  = (const float*)d_in[6];
  const float* aWr  = (const float*)d_in[7];
  const float* aWe  = (const float*)d_in[8];
  const float* aAtt = (const float*)d_in[9];
  const float* aB   = (const float*)d_in[10];
  const float* cWl  = (const float*)d_in[11];
  const float* cWr  = (const float*)d_in[12];
  const float* cWe  = (const float*)d_in[13];
  const float* cAtt = (const float*)d_in[14];
  const float* cB   = (const float*)d_in[15];
  const float* Wa   = (const float*)d_in[16];
  const float* ba   = (const float*)d_in[17];
  const float* Wv   = (const float*)d_in[18];
  const float* bv   = (const float*)d_in[19];
  const int* src    = (const int*)d_in[20];
  const int* dst    = (const int*)d_in[21];
  float* out = (float*)d_out;

  char* w = (char*)d_ws;
  size_t off = 0;
  auto alloc = [&](size_t bytes) -> char* {
    char* p = w + off;
    off = (off + bytes + 255) & ~(size_t)255;
    return p;
  };
  float* h0  = (float*)alloc((size_t)N_NODES * ENC * 4);
  float* hA  = (float*)alloc((size_t)N_NODES * ENC * 4);
  float* hC  = (float*)alloc((size_t)N_NODES * ENC * 4);
  float* xl_comb = (float*)alloc((size_t)N_NODES * 2 * ENC * 4);  // [n][stack][64]
  float* xr_comb = (float*)alloc((size_t)N_NODES * 2 * ENC * 4);  // [n][stack][64]
  int* eid       = (int*)alloc((size_t)N_EDGES * 4);
  int* srcs      = (int*)alloc((size_t)N_EDGES * 4);
  float* ea_perm = (float*)alloc((size_t)N_EDGES * 16);
  int* row_start = (int*)alloc((size_t)(N_NODES + 1) * 4);
  int* cursor    = (int*)alloc((size_t)N_NODES * 4);
  int* part      = (int*)alloc(256 * 4);
  float* wcomb   = (float*)alloc(6 * 4 * ENC * 4);
  float* bcomb   = (float*)alloc(6 * ENC * 4);

  // ---- CSR build ----
  hipMemsetAsync(cursor, 0, (size_t)N_NODES * 4, stream);
  k_hist<<<2048, 256, 0, stream>>>(dst, cursor);
  k_red<<<SCAN_BLOCKS, 256, 0, stream>>>(cursor, part);
  k_scanp<<<1, 256, 0, stream>>>(part);
  k_csr<<<SCAN_BLOCKS, 256, 0, stream>>>(cursor, part, row_start);
  k_scatter<<<2048, 256, 0, stream>>>(dst, cursor, eid);
  k_gather<<<2048, 256, 0, stream>>>(eid, src, ea, srcs, ea_perm);

  // ---- encoder (+ folded edge weights in block 0) ----
  k_encode<<<512, 256, 0, stream>>>(x, Wn, bn, h0, Wedg, bedg, aWe, cWe, wcomb, bcomb);

  const int GEMM_TILES = (N_NODES + 63) / 64;  // 782

  for (int r = 0; r < ROUNDS; ++r) {
    const float* hinA = (r == 0) ? h0 : hA;
    const float* hinC = (r == 0) ? h0 : hC;
    k_gemm2<<<dim3(GEMM_TILES, 2), 256, 0, stream>>>(
        hinA, hinC, aWl + r * ENC * ENC, aWr + r * ENC * ENC, bcomb + r * ENC,
        cWl + r * ENC * ENC, cWr + r * ENC * ENC, bcomb + (3 + r) * ENC,
        xl_comb, xr_comb);
    if (r < ROUNDS - 1)
      k_attn<1><<<2048, 256, 0, stream>>>(row_start, srcs, ea_perm, xl_comb, xr_comb,
                                          wcomb + r * 4 * ENC, wcomb + (3 + r) * 4 * ENC,
                                          aAtt + r * ENC, cAtt + r * ENC,
                                          aB + r * ENC, cB + r * ENC, hA, hC,
                                          Wa, ba, Wv, bv, out);
    else
      k_attn<0><<<2048, 256, 0, stream>>>(row_start, srcs, ea_perm, xl_comb, xr_comb,
                                          wcomb + r * 4 * ENC, wcomb + (3 + r) * 4 * ENC,
                                          aAtt + r * ENC, cAtt + r * ENC,
                                          aB + r * ENC, cB + r * ENC, hA, hC,
                                          Wa, ba, Wv, bv, out);
  }
}